// Round 9
// baseline (226.472 us; speedup 1.0000x reference)
//
#include <hip/hip_runtime.h>
#include <hip/hip_bf16.h>

typedef short bf16x8 __attribute__((ext_vector_type(8)));
typedef float f32x4 __attribute__((ext_vector_type(4)));
typedef unsigned int u32x4 __attribute__((ext_vector_type(4)));

static __device__ __forceinline__ unsigned short f2bf(float f) {
  unsigned int u = __builtin_bit_cast(unsigned int, f);
  u += 0x7fffu + ((u >> 16) & 1u);
  return (unsigned short)(u >> 16);
}
static __device__ __forceinline__ float bf2f(unsigned short b) {
  unsigned int u = ((unsigned int)b) << 16;
  return __builtin_bit_cast(float, u);
}

// ============ fused0: blocks 0-511 proj+whs1 (+pmax1); blocks 512-2559 adj->mask ============
__global__ __launch_bounds__(256) void fused0_kernel(
    const int* __restrict__ adj, unsigned char* __restrict__ maskb,
    const float* __restrict__ x, const float* __restrict__ Wp,
    const float* __restrict__ bp, const float* __restrict__ W1,
    const float* __restrict__ a1, unsigned short* __restrict__ WhT1,
    float* __restrict__ s_src1, float* __restrict__ s_dst1, float* __restrict__ pmax1) {
  __shared__ float xs[16][256];
  __shared__ float hsh[16][128];
  __shared__ float rsv[2][16][2];
  __shared__ float sdv[16];
  int tid = threadIdx.x;
  int b = blockIdx.x;
  if (b >= 512) {  // ---- mask part: 1 wave per row, perfectly sequential stream ----
    int wid = (b - 512) * 4 + (tid >> 6);
    int lane = tid & 63;
    const int4* ap = reinterpret_cast<const int4*>(adj + (size_t)wid * 8192);
    unsigned char* mrow = maskb + (size_t)wid * 1024;
#pragma unroll 4
    for (int it = 0; it < 16; ++it) {
      int cbase = it * 512;
      int4 a0 = ap[(cbase >> 2) + lane * 2];
      int4 a1v = ap[(cbase >> 2) + lane * 2 + 1];
      unsigned int mb = (unsigned)((a0.x > 0) | ((a0.y > 0) << 1) | ((a0.z > 0) << 2) |
                                   ((a0.w > 0) << 3) | ((a1v.x > 0) << 4) |
                                   ((a1v.y > 0) << 5) | ((a1v.z > 0) << 6) |
                                   ((a1v.w > 0) << 7));
      mrow[(cbase >> 3) + lane] = (unsigned char)mb;
    }
    return;
  }
  // ---- proj + whs1 part: 16 rows, 256 threads (j = tid&127, half = tid>>7) ----
  int r0 = b * 16;
  int j = tid & 127, half = tid >> 7;
  for (int t = tid; t < 16 * 256; t += 256)
    xs[t >> 8][t & 255] = x[(size_t)(r0 + (t >> 8)) * 256 + (t & 255)];
  __syncthreads();
  {
    float acc[8];
#pragma unroll
    for (int r = 0; r < 8; ++r) acc[r] = 0.f;
    const float4* wp4 = reinterpret_cast<const float4*>(Wp + (size_t)j * 256);
#pragma unroll 4
    for (int k4 = 0; k4 < 64; ++k4) {
      float4 w = wp4[k4];
#pragma unroll
      for (int r = 0; r < 8; ++r) {
        float4 xv = *reinterpret_cast<const float4*>(&xs[half * 8 + r][k4 * 4]);
        acc[r] = fmaf(xv.x, w.x, acc[r]);
        acc[r] = fmaf(xv.y, w.y, acc[r]);
        acc[r] = fmaf(xv.z, w.z, acc[r]);
        acc[r] = fmaf(xv.w, w.w, acc[r]);
      }
    }
    float bb = bp[j];
#pragma unroll
    for (int r = 0; r < 8; ++r) {
      float v = acc[r] + bb;
      hsh[half * 8 + r][j] = v > 0.f ? v : 0.f;
    }
  }
  __syncthreads();
  {
    float acc2[8];
#pragma unroll
    for (int r = 0; r < 8; ++r) acc2[r] = 0.f;
    const float4* w14 = reinterpret_cast<const float4*>(W1 + (size_t)j * 128);
#pragma unroll 4
    for (int k4 = 0; k4 < 32; ++k4) {
      float4 w = w14[k4];
#pragma unroll
      for (int r = 0; r < 8; ++r) {
        float4 xv = *reinterpret_cast<const float4*>(&hsh[half * 8 + r][k4 * 4]);
        acc2[r] = fmaf(xv.x, w.x, acc2[r]);
        acc2[r] = fmaf(xv.y, w.y, acc2[r]);
        acc2[r] = fmaf(xv.z, w.z, acc2[r]);
        acc2[r] = fmaf(xv.w, w.w, acc2[r]);
      }
    }
    float asrc = a1[j], adst = a1[128 + j];
    int lane = tid & 63, wv = tid >> 6;
#pragma unroll
    for (int r = 0; r < 8; ++r) {
      int rr = r0 + half * 8 + r;
      WhT1[(size_t)(rr >> 5) * (128 * 32) + (size_t)j * 32 + (rr & 31)] = f2bf(acc2[r]);
      float vs = acc2[r] * asrc, vd = acc2[r] * adst;
#pragma unroll
      for (int off = 32; off; off >>= 1) {
        vs += __shfl_xor(vs, off);
        vd += __shfl_xor(vd, off);
      }
      if (lane == 0) { rsv[0][half * 8 + r][wv & 1] = vs; rsv[1][half * 8 + r][wv & 1] = vd; }
    }
    __syncthreads();
    if (tid < 16) {
      float vs = rsv[0][tid][0] + rsv[0][tid][1];
      float vd = rsv[1][tid][0] + rsv[1][tid][1];
      s_src1[r0 + tid] = vs;
      s_dst1[r0 + tid] = vd;
      sdv[tid] = vd;
    }
    __syncthreads();
    if (tid == 0) {
      float m = sdv[0];
#pragma unroll
      for (int i = 1; i < 16; ++i) m = fmaxf(m, sdv[i]);
      pmax1[b] = m;
    }
  }
}

// p = max(A*B, C*D) masked = exact softmax weight exp(lrelu(e)-m); pack pair->bf16 trunc
static __device__ __forceinline__ bf16x8 buildp(float Af, float Cf, float4 ba, float4 bb,
                                                float4 da, float4 db, unsigned int mb) {
  float bv[8] = {ba.x, ba.y, ba.z, ba.w, bb.x, bb.y, bb.z, bb.w};
  float dv[8] = {da.x, da.y, da.z, da.w, db.x, db.y, db.z, db.w};
  u32x4 pw;
#pragma unroll
  for (int q = 0; q < 4; ++q) {
    float plo = fmaxf(Af * bv[2 * q], Cf * dv[2 * q]);
    float phi = fmaxf(Af * bv[2 * q + 1], Cf * dv[2 * q + 1]);
    plo = ((mb >> (2 * q)) & 1u) ? plo : 0.f;
    phi = ((mb >> (2 * q + 1)) & 1u) ? phi : 0.f;
    pw[q] = __builtin_amdgcn_perm(__builtin_bit_cast(unsigned int, phi),
                                  __builtin_bit_cast(unsigned int, plo), 0x07060302u);
  }
  return __builtin_bit_cast(bf16x8, pw);
}

// ============ attn: 8-wave block, LDS-staged WhT (PADDED rows: stride 40 shorts) ============
// Row stride 40 shorts (80B, dword stride 20): banks (20*rsub+4*kg) mod 32 give 8 distinct
// 4-bank groups; only rsub vs rsub+8 alias (2-way = free). Eliminates the 8-way conflict
// of the previous 64B-stride layout. B/D loaded per-ks from LDS to trim live VGPRs.
template <int F>
__global__ __launch_bounds__(512, 2) void attn_kernel(
    const unsigned char* __restrict__ maskb, const float* __restrict__ s_src,
    const float* __restrict__ s_dst, const float* __restrict__ pmax,
    const unsigned short* __restrict__ WhT, unsigned short* __restrict__ pacc,
    float* __restrict__ pl, int cps) {
  constexpr int NP = F / 64;        // int4 staging chunks per thread
  constexpr int RS = 40;            // padded row stride in shorts
  __shared__ unsigned short lds[2][2 * F * RS];  // [buf][ks*F*RS + j*RS + col]
  __shared__ float Bl[2048], Dl[2048];
  __shared__ float2 ACl[256];
  __shared__ float red[8];
  int tid = threadIdx.x;
  int lane = tid & 63, wv = tid >> 6;
  int rsub = lane & 15, kg = lane >> 4;
  int r0 = blockIdx.x * 256 + wv * 32;
  int cbeg = blockIdx.y * cps;
  int ntile = cps >> 6;

  // staging chunk -> padded LDS dest (16B aligned: j*80 + s8*16 + ks*F*80)
  int sdest[NP];
#pragma unroll
  for (int p = 0; p < NP; ++p) {
    int c = tid + p * 512;
    int ks = c / (F * 4), rem = c % (F * 4);
    sdest[p] = ks * (F * RS) + (rem >> 2) * RS + (rem & 3) * 8;
  }

  // ---- prologue: fold g, fill B/D/AC, stage tile 0 ----
  float pv = pmax[tid & 511];
#pragma unroll
  for (int off = 32; off; off >>= 1) pv = fmaxf(pv, __shfl_xor(pv, off));
  if (lane == 0) red[wv] = pv;
  __syncthreads();
  float g = red[0];
#pragma unroll
  for (int i = 1; i < 8; ++i) g = fmaxf(g, red[i]);
  for (int t = tid; t < cps; t += 512) {
    float sd = s_dst[cbeg + t] - g;
    Bl[t] = __expf(sd);
    Dl[t] = __expf(0.2f * sd);
  }
  if (tid < 256) {
    float e0 = s_src[blockIdx.x * 256 + tid] + g;
    ACl[tid] = make_float2(__expf(fminf(0.8f * e0, 0.f)), __expf(fminf(-0.8f * e0, 0.f)));
  }
  const int4* gw = reinterpret_cast<const int4*>(WhT + (size_t)(cbeg >> 5) * (F * 32));
  {
    int4 s0[NP];
#pragma unroll
    for (int p = 0; p < NP; ++p) s0[p] = gw[tid + p * 512];
#pragma unroll
    for (int p = 0; p < NP; ++p)
      *reinterpret_cast<int4*>(&lds[0][sdest[p]]) = s0[p];
  }
  __syncthreads();

  float2 ac0 = ACl[wv * 32 + rsub], ac1 = ACl[wv * 32 + 16 + rsub];
  int row0 = r0 + rsub, row1 = r0 + 16 + rsub;
  const unsigned long long* mq0 = reinterpret_cast<const unsigned long long*>(
      maskb + (size_t)row0 * 1024 + (cbeg >> 3));
  const unsigned long long* mq1 = reinterpret_cast<const unsigned long long*>(
      maskb + (size_t)row1 * 1024 + (cbeg >> 3));
  f32x4 acc0[F / 16], acc1[F / 16];
#pragma unroll
  for (int t = 0; t < F / 16; ++t) { acc0[t] = (f32x4)0.f; acc1[t] = (f32x4)0.f; }
  f32x4 accl0 = (f32x4)0.f, accl1 = (f32x4)0.f;
  bf16x8 ones;
#pragma unroll
  for (int jj = 0; jj < 8; ++jj) ones[jj] = (short)0x3F80;  // bf16 1.0
  const int rowoff = rsub * RS + kg * 8;

  for (int tt = 0; tt < ntile; ++tt) {
    int bi = tt & 1;
    bool more = tt + 1 < ntile;
    // ---- early: next-tile staging loads + this tile's mask loads ----
    int4 sg[NP];
    if (more) {
#pragma unroll
      for (int p = 0; p < NP; ++p) sg[p] = gw[(tt + 1) * (F * 8) + tid + p * 512];
    }
    unsigned long long mv0 = mq0[tt], mv1 = mq1[tt];
    int cl = tt * 64 + kg * 8;
    __builtin_amdgcn_sched_barrier(0);
    // ---- compute on buf bi ----
    {  // ks = 0
      const unsigned short* lbk = &lds[bi][0];
      bf16x8 bfrag[F / 16];
#pragma unroll
      for (int t = 0; t < F / 16; ++t)
        bfrag[t] = *reinterpret_cast<const bf16x8*>(lbk + t * (16 * RS) + rowoff);
      float4 bA0 = *reinterpret_cast<const float4*>(&Bl[cl]);
      float4 bA1 = *reinterpret_cast<const float4*>(&Bl[cl + 4]);
      float4 dA0 = *reinterpret_cast<const float4*>(&Dl[cl]);
      float4 dA1 = *reinterpret_cast<const float4*>(&Dl[cl + 4]);
      unsigned sh = kg * 8;
      bf16x8 af0 = buildp(ac0.x, ac0.y, bA0, bA1, dA0, dA1, (unsigned)(mv0 >> sh) & 0xffu);
      accl0 = __builtin_amdgcn_mfma_f32_16x16x32_bf16(af0, ones, accl0, 0, 0, 0);
#pragma unroll
      for (int t = 0; t < F / 16; ++t)
        acc0[t] = __builtin_amdgcn_mfma_f32_16x16x32_bf16(af0, bfrag[t], acc0[t], 0, 0, 0);
      bf16x8 af1 = buildp(ac1.x, ac1.y, bA0, bA1, dA0, dA1, (unsigned)(mv1 >> sh) & 0xffu);
      accl1 = __builtin_amdgcn_mfma_f32_16x16x32_bf16(af1, ones, accl1, 0, 0, 0);
#pragma unroll
      for (int t = 0; t < F / 16; ++t)
        acc1[t] = __builtin_amdgcn_mfma_f32_16x16x32_bf16(af1, bfrag[t], acc1[t], 0, 0, 0);
    }
    {  // ks = 1
      const unsigned short* lbk = &lds[bi][F * RS];
      bf16x8 bfrag[F / 16];
#pragma unroll
      for (int t = 0; t < F / 16; ++t)
        bfrag[t] = *reinterpret_cast<const bf16x8*>(lbk + t * (16 * RS) + rowoff);
      float4 bB0 = *reinterpret_cast<const float4*>(&Bl[cl + 32]);
      float4 bB1 = *reinterpret_cast<const float4*>(&Bl[cl + 36]);
      float4 dB0 = *reinterpret_cast<const float4*>(&Dl[cl + 32]);
      float4 dB1 = *reinterpret_cast<const float4*>(&Dl[cl + 36]);
      unsigned sh = 32 + kg * 8;
      bf16x8 af0 = buildp(ac0.x, ac0.y, bB0, bB1, dB0, dB1, (unsigned)(mv0 >> sh) & 0xffu);
      accl0 = __builtin_amdgcn_mfma_f32_16x16x32_bf16(af0, ones, accl0, 0, 0, 0);
#pragma unroll
      for (int t = 0; t < F / 16; ++t)
        acc0[t] = __builtin_amdgcn_mfma_f32_16x16x32_bf16(af0, bfrag[t], acc0[t], 0, 0, 0);
      bf16x8 af1 = buildp(ac1.x, ac1.y, bB0, bB1, dB0, dB1, (unsigned)(mv1 >> sh) & 0xffu);
      accl1 = __builtin_amdgcn_mfma_f32_16x16x32_bf16(af1, ones, accl1, 0, 0, 0);
#pragma unroll
      for (int t = 0; t < F / 16; ++t)
        acc1[t] = __builtin_amdgcn_mfma_f32_16x16x32_bf16(af1, bfrag[t], acc1[t], 0, 0, 0);
    }
    __builtin_amdgcn_sched_barrier(0);
    // ---- late: LDS write of staged tile ----
    if (more) {
#pragma unroll
      for (int p = 0; p < NP; ++p)
        *reinterpret_cast<int4*>(&lds[bi ^ 1][sdest[p]]) = sg[p];
    }
    __syncthreads();
  }

  size_t plb = (size_t)blockIdx.y * 8192;
  if (rsub == 0) {
#pragma unroll
    for (int q = 0; q < 4; ++q) {
      pl[plb + r0 + kg * 4 + q] = accl0[q];
      pl[plb + r0 + 16 + kg * 4 + q] = accl1[q];
    }
  }
  size_t pb = (size_t)blockIdx.y * 8192 * F;
#pragma unroll
  for (int t = 0; t < F / 16; ++t) {
    int col = t * 16 + rsub;
#pragma unroll
    for (int q = 0; q < 4; ++q) {
      pacc[pb + (size_t)(r0 + kg * 4 + q) * F + col] = f2bf(acc0[t][q]);
      pacc[pb + (size_t)(r0 + 16 + kg * 4 + q) * F + col] = f2bf(acc1[t][q]);
    }
  }
}

// ====== whs2e: epi1 fused (pacc1/pl1 -> ELU h1 tile in LDS) + whs (F=64) + pmax2 ======
__global__ __launch_bounds__(128) void whs2e_kernel(
    const unsigned short* __restrict__ pacc1, const float* __restrict__ pl1,
    const float* __restrict__ W2, const float* __restrict__ a2,
    unsigned short* __restrict__ WhT2, float* __restrict__ s_src2,
    float* __restrict__ s_dst2, float* __restrict__ pmax2, int S) {
  __shared__ float hsh[16][128];
  __shared__ float sdv[16];
  int tid = threadIdx.x;
  int r0 = blockIdx.x * 16;
  int c2 = tid & 63, half = tid >> 6;
  for (int i = 0; i < 8; ++i) {
    int rr = r0 + half * 8 + i;
    float l = 0.f;
    for (int s = 0; s < S; ++s) l += pl1[(size_t)s * 8192 + rr];
    float a0 = 0.f, a1v = 0.f;
    for (int s = 0; s < S; ++s) {
      unsigned u = *reinterpret_cast<const unsigned*>(
          pacc1 + (size_t)s * (8192 * 128) + (size_t)rr * 128 + c2 * 2);
      a0 += bf2f((unsigned short)(u & 0xffffu));
      a1v += bf2f((unsigned short)(u >> 16));
    }
    float v0 = a0 / l, v1 = a1v / l;
    v0 = v0 > 0.f ? v0 : expm1f(v0);
    v1 = v1 > 0.f ? v1 : expm1f(v1);
    hsh[half * 8 + i][c2 * 2] = v0;
    hsh[half * 8 + i][c2 * 2 + 1] = v1;
  }
  __syncthreads();
  float acc2[8];
#pragma unroll
  for (int r = 0; r < 8; ++r) acc2[r] = 0.f;
  const float4* w24 = reinterpret_cast<const float4*>(W2 + (size_t)c2 * 128);
#pragma unroll 4
  for (int k4 = 0; k4 < 32; ++k4) {
    float4 w = w24[k4];
#pragma unroll
    for (int r = 0; r < 8; ++r) {
      float4 xv = *reinterpret_cast<const float4*>(&hsh[half * 8 + r][k4 * 4]);
      acc2[r] = fmaf(xv.x, w.x, acc2[r]);
      acc2[r] = fmaf(xv.y, w.y, acc2[r]);
      acc2[r] = fmaf(xv.z, w.z, acc2[r]);
      acc2[r] = fmaf(xv.w, w.w, acc2[r]);
    }
  }
  float asrc = a2[c2], adst = a2[64 + c2];
  int lane = tid & 63;
#pragma unroll
  for (int r = 0; r < 8; ++r) {
    int rr = r0 + half * 8 + r;
    WhT2[(size_t)(rr >> 5) * (64 * 32) + (size_t)c2 * 32 + (rr & 31)] = f2bf(acc2[r]);
    float vs = acc2[r] * asrc, vd = acc2[r] * adst;
#pragma unroll
    for (int off = 32; off; off >>= 1) {
      vs += __shfl_xor(vs, off);
      vd += __shfl_xor(vd, off);
    }
    if (lane == 0) { s_src2[rr] = vs; s_dst2[rr] = vd; sdv[half * 8 + r] = vd; }
  }
  __syncthreads();
  if (tid == 0) {
    float m = sdv[0];
#pragma unroll
    for (int i = 1; i < 16; ++i) m = fmaxf(m, sdv[i]);
    pmax2[blockIdx.x] = m;
  }
}

// -------- epi2: out = (sum_s pacc2) / (sum_s l), no ELU --------
__global__ void epi_kernel(const unsigned short* __restrict__ pacc,
                           const float* __restrict__ pl, float* __restrict__ out, int S) {
  int idx = blockIdx.x * 256 + threadIdx.x;
  int row = idx >> 6;
  float l = 0.f, a = 0.f;
  for (int s = 0; s < S; ++s) {
    l += pl[(size_t)s * 8192 + row];
    a += bf2f(pacc[(size_t)s * 8192 * 64 + idx]);
  }
  out[idx] = a / l;
}

extern "C" void kernel_launch(void* const* d_in, const int* in_sizes, int n_in,
                              void* d_out, int out_size, void* d_ws, size_t ws_size,
                              hipStream_t stream) {
  const float* x  = (const float*)d_in[0];
  const int* adj  = (const int*)d_in[1];
  const float* Wp = (const float*)d_in[2];
  const float* bp = (const float*)d_in[3];
  const float* W1 = (const float*)d_in[4];
  const float* a1 = (const float*)d_in[5];
  const float* W2 = (const float*)d_in[6];
  const float* a2 = (const float*)d_in[7];
  float* out = (float*)d_out;

  // workspace: 18 MiB fixed + S*3 MiB (bf16 partials)
  int S = 4;
  if (ws_size >= (18ull + 48) * 1024 * 1024) S = 16;
  else if (ws_size >= (18ull + 24) * 1024 * 1024) S = 8;
  int cps = 8192 / S;

  char* ws = (char*)d_ws;
  unsigned short* WhT1 = (unsigned short*)(ws + 0);             // 0-2 MiB
  unsigned short* WhT2 = (unsigned short*)(ws + (2ull << 20));  // 2-3
  char* sm = ws + (3ull << 20);
  float* s_src1 = (float*)(sm + 0 * 32768);
  float* s_dst1 = (float*)(sm + 1 * 32768);
  float* s_src2 = (float*)(sm + 2 * 32768);
  float* s_dst2 = (float*)(sm + 3 * 32768);
  float* pmax1  = (float*)(sm + 4 * 32768);
  float* pmax2  = (float*)(sm + 4 * 32768 + 4096);
  unsigned char* maskb = (unsigned char*)(ws + (8ull << 20));   // 8-16 MiB
  float* pl1    = (float*)(ws + (16ull << 20));                 // 16-17
  float* pl2    = (float*)(ws + (17ull << 20));                 // 17-18
  unsigned short* pacc1 = (unsigned short*)(ws + (18ull << 20));        // S*2 MiB
  unsigned short* pacc2 = pacc1 + (size_t)S * 8192 * 128;               // S*1 MiB

  fused0_kernel<<<2560, 256, 0, stream>>>(adj, maskb, x, Wp, bp, W1, a1, WhT1,
                                          s_src1, s_dst1, pmax1);
  attn_kernel<128><<<dim3(32, S), 512, 0, stream>>>(
      maskb, s_src1, s_dst1, pmax1, WhT1, pacc1, pl1, cps);
  whs2e_kernel<<<512, 128, 0, stream>>>(pacc1, pl1, W2, a2, WhT2, s_src2, s_dst2,
                                        pmax2, S);
  attn_kernel<64><<<dim3(32, S), 512, 0, stream>>>(
      maskb, s_src2, s_dst2, pmax2, WhT2, pacc2, pl2, cps);
  epi_kernel<<<2048, 256, 0, stream>>>(pacc2, pl2, out, S);
}

// Round 10
// 200.634 us; speedup vs baseline: 1.1288x; 1.1288x over previous
//
#include <hip/hip_runtime.h>
#include <hip/hip_bf16.h>

typedef short bf16x8 __attribute__((ext_vector_type(8)));
typedef float f32x4 __attribute__((ext_vector_type(4)));
typedef unsigned int u32x4 __attribute__((ext_vector_type(4)));

static __device__ __forceinline__ unsigned short f2bf(float f) {
  unsigned int u = __builtin_bit_cast(unsigned int, f);
  u += 0x7fffu + ((u >> 16) & 1u);
  return (unsigned short)(u >> 16);
}
static __device__ __forceinline__ float bf2f(unsigned short b) {
  unsigned int u = ((unsigned int)b) << 16;
  return __builtin_bit_cast(float, u);
}

// ============ fused0: blocks 0-511 proj+whs1 (+pmax1); blocks 512-2559 adj->mask ============
__global__ __launch_bounds__(256) void fused0_kernel(
    const int* __restrict__ adj, unsigned char* __restrict__ maskb,
    const float* __restrict__ x, const float* __restrict__ Wp,
    const float* __restrict__ bp, const float* __restrict__ W1,
    const float* __restrict__ a1, unsigned short* __restrict__ WhT1,
    float* __restrict__ s_src1, float* __restrict__ s_dst1, float* __restrict__ pmax1) {
  __shared__ float xs[16][256];
  __shared__ float hsh[16][128];
  __shared__ float rsv[2][16][2];
  __shared__ float sdv[16];
  int tid = threadIdx.x;
  int b = blockIdx.x;
  if (b >= 512) {  // ---- mask part: 1 wave per row, perfectly sequential stream ----
    int wid = (b - 512) * 4 + (tid >> 6);
    int lane = tid & 63;
    const int4* ap = reinterpret_cast<const int4*>(adj + (size_t)wid * 8192);
    unsigned char* mrow = maskb + (size_t)wid * 1024;
#pragma unroll 4
    for (int it = 0; it < 16; ++it) {
      int cbase = it * 512;
      int4 a0 = ap[(cbase >> 2) + lane * 2];
      int4 a1v = ap[(cbase >> 2) + lane * 2 + 1];
      unsigned int mb = (unsigned)((a0.x > 0) | ((a0.y > 0) << 1) | ((a0.z > 0) << 2) |
                                   ((a0.w > 0) << 3) | ((a1v.x > 0) << 4) |
                                   ((a1v.y > 0) << 5) | ((a1v.z > 0) << 6) |
                                   ((a1v.w > 0) << 7));
      mrow[(cbase >> 3) + lane] = (unsigned char)mb;
    }
    return;
  }
  // ---- proj + whs1 part: 16 rows, 256 threads (j = tid&127, half = tid>>7) ----
  int r0 = b * 16;
  int j = tid & 127, half = tid >> 7;
  for (int t = tid; t < 16 * 256; t += 256)
    xs[t >> 8][t & 255] = x[(size_t)(r0 + (t >> 8)) * 256 + (t & 255)];
  __syncthreads();
  {
    float acc[8];
#pragma unroll
    for (int r = 0; r < 8; ++r) acc[r] = 0.f;
    const float4* wp4 = reinterpret_cast<const float4*>(Wp + (size_t)j * 256);
#pragma unroll 4
    for (int k4 = 0; k4 < 64; ++k4) {
      float4 w = wp4[k4];
#pragma unroll
      for (int r = 0; r < 8; ++r) {
        float4 xv = *reinterpret_cast<const float4*>(&xs[half * 8 + r][k4 * 4]);
        acc[r] = fmaf(xv.x, w.x, acc[r]);
        acc[r] = fmaf(xv.y, w.y, acc[r]);
        acc[r] = fmaf(xv.z, w.z, acc[r]);
        acc[r] = fmaf(xv.w, w.w, acc[r]);
      }
    }
    float bb = bp[j];
#pragma unroll
    for (int r = 0; r < 8; ++r) {
      float v = acc[r] + bb;
      hsh[half * 8 + r][j] = v > 0.f ? v : 0.f;
    }
  }
  __syncthreads();
  {
    float acc2[8];
#pragma unroll
    for (int r = 0; r < 8; ++r) acc2[r] = 0.f;
    const float4* w14 = reinterpret_cast<const float4*>(W1 + (size_t)j * 128);
#pragma unroll 4
    for (int k4 = 0; k4 < 32; ++k4) {
      float4 w = w14[k4];
#pragma unroll
      for (int r = 0; r < 8; ++r) {
        float4 xv = *reinterpret_cast<const float4*>(&hsh[half * 8 + r][k4 * 4]);
        acc2[r] = fmaf(xv.x, w.x, acc2[r]);
        acc2[r] = fmaf(xv.y, w.y, acc2[r]);
        acc2[r] = fmaf(xv.z, w.z, acc2[r]);
        acc2[r] = fmaf(xv.w, w.w, acc2[r]);
      }
    }
    float asrc = a1[j], adst = a1[128 + j];
    int lane = tid & 63, wv = tid >> 6;
#pragma unroll
    for (int r = 0; r < 8; ++r) {
      int rr = r0 + half * 8 + r;
      WhT1[(size_t)(rr >> 5) * (128 * 32) + (size_t)j * 32 + (rr & 31)] = f2bf(acc2[r]);
      float vs = acc2[r] * asrc, vd = acc2[r] * adst;
#pragma unroll
      for (int off = 32; off; off >>= 1) {
        vs += __shfl_xor(vs, off);
        vd += __shfl_xor(vd, off);
      }
      if (lane == 0) { rsv[0][half * 8 + r][wv & 1] = vs; rsv[1][half * 8 + r][wv & 1] = vd; }
    }
    __syncthreads();
    if (tid < 16) {
      float vs = rsv[0][tid][0] + rsv[0][tid][1];
      float vd = rsv[1][tid][0] + rsv[1][tid][1];
      s_src1[r0 + tid] = vs;
      s_dst1[r0 + tid] = vd;
      sdv[tid] = vd;
    }
    __syncthreads();
    if (tid == 0) {
      float m = sdv[0];
#pragma unroll
      for (int i = 1; i < 16; ++i) m = fmaxf(m, sdv[i]);
      pmax1[b] = m;
    }
  }
}

// p = max(A*B, C*D) masked = exact softmax weight exp(lrelu(e)-m); pack pair->bf16 trunc
static __device__ __forceinline__ bf16x8 buildp(float Af, float Cf, float4 ba, float4 bb,
                                                float4 da, float4 db, unsigned int mb) {
  float bv[8] = {ba.x, ba.y, ba.z, ba.w, bb.x, bb.y, bb.z, bb.w};
  float dv[8] = {da.x, da.y, da.z, da.w, db.x, db.y, db.z, db.w};
  u32x4 pw;
#pragma unroll
  for (int q = 0; q < 4; ++q) {
    float plo = fmaxf(Af * bv[2 * q], Cf * dv[2 * q]);
    float phi = fmaxf(Af * bv[2 * q + 1], Cf * dv[2 * q + 1]);
    plo = ((mb >> (2 * q)) & 1u) ? plo : 0.f;
    phi = ((mb >> (2 * q + 1)) & 1u) ? phi : 0.f;
    pw[q] = __builtin_amdgcn_perm(__builtin_bit_cast(unsigned int, phi),
                                  __builtin_bit_cast(unsigned int, plo), 0x07060302u);
  }
  return __builtin_bit_cast(bf16x8, pw);
}

// ============ attn: 8-wave block, LDS WhT (padded) + LDS mask strip (chunked preload) ============
// Mask strip preloaded per 8-tile chunk: coalesced full-line loads once, per-tile reads
// from LDS (kills the 32-line-per-instruction recurring gather that thrashes L1).
// WhT rows padded to 40 shorts (per-8-lane-phase conflict-free b128 reads).
// pacc layout [row][S][F], pl [row][S] for coalesced downstream reads.
template <int F>
__global__ __launch_bounds__(512, 2) void attn_kernel(
    const unsigned char* __restrict__ maskb, const float* __restrict__ s_src,
    const float* __restrict__ s_dst, const float* __restrict__ pmax,
    const unsigned short* __restrict__ WhT, unsigned short* __restrict__ pacc,
    float* __restrict__ pl, int cps, int S) {
  constexpr int NP = F / 64;        // int4 staging chunks per thread
  constexpr int RS = 40;            // padded WhT row stride in shorts
  __shared__ unsigned short lds[2][2 * F * RS];  // [buf][ks*F*RS + j*RS + col]
  __shared__ int4 mskl4[256 * 5];   // mask strip: 256 rows x 80B (64B data + 16B pad)
  __shared__ float Bl[2048], Dl[2048];
  __shared__ float2 ACl[256];
  __shared__ float red[8];
  int tid = threadIdx.x;
  int lane = tid & 63, wv = tid >> 6;
  int rsub = lane & 15, kg = lane >> 4;
  int r0b = blockIdx.x * 256;
  int r0 = r0b + wv * 32;
  int by = blockIdx.y;
  int cbeg = by * cps;
  int ntile = cps >> 6;
  const unsigned char* mskb = reinterpret_cast<const unsigned char*>(mskl4);

  // staging chunk -> padded LDS dest (shorts): ks*(F*RS) + j*RS + s8*8
  int sdest[NP];
#pragma unroll
  for (int p = 0; p < NP; ++p) {
    int c = tid + p * 512;
    int ks = c / (F * 4), rem = c % (F * 4);
    sdest[p] = ks * (F * RS) + (rem >> 2) * RS + (rem & 3) * 8;
  }

  // ---- prologue: fold g, fill B/D/AC, stage tile 0 ----
  float pv = pmax[tid & 511];
#pragma unroll
  for (int off = 32; off; off >>= 1) pv = fmaxf(pv, __shfl_xor(pv, off));
  if (lane == 0) red[wv] = pv;
  __syncthreads();
  float g = red[0];
#pragma unroll
  for (int i = 1; i < 8; ++i) g = fmaxf(g, red[i]);
  for (int t = tid; t < cps; t += 512) {
    float sd = s_dst[cbeg + t] - g;
    Bl[t] = __expf(sd);
    Dl[t] = __expf(0.2f * sd);
  }
  if (tid < 256) {
    float e0 = s_src[r0b + tid] + g;
    ACl[tid] = make_float2(__expf(fminf(0.8f * e0, 0.f)), __expf(fminf(-0.8f * e0, 0.f)));
  }
  const int4* gw = reinterpret_cast<const int4*>(WhT + (size_t)(cbeg >> 5) * (F * 32));
  {
    int4 s0[NP];
#pragma unroll
    for (int p = 0; p < NP; ++p) s0[p] = gw[tid + p * 512];
#pragma unroll
    for (int p = 0; p < NP; ++p)
      *reinterpret_cast<int4*>(&lds[0][sdest[p]]) = s0[p];
  }
  __syncthreads();

  float2 ac0 = ACl[wv * 32 + rsub], ac1 = ACl[wv * 32 + 16 + rsub];
  f32x4 acc0[F / 16], acc1[F / 16];
#pragma unroll
  for (int t = 0; t < F / 16; ++t) { acc0[t] = (f32x4)0.f; acc1[t] = (f32x4)0.f; }
  f32x4 accl0 = (f32x4)0.f, accl1 = (f32x4)0.f;
  bf16x8 ones;
#pragma unroll
  for (int jj = 0; jj < 8; ++jj) ones[jj] = (short)0x3F80;  // bf16 1.0
  const int rowoff = rsub * RS + kg * 8;
  const int mrow0 = (wv * 32 + rsub) * 80, mrow1 = (wv * 32 + 16 + rsub) * 80;

  for (int tt = 0; tt < ntile; ++tt) {
    // ---- chunk boundary: preload 8 tiles' mask strip (coalesced, full 64B lines) ----
    if ((tt & 7) == 0) {
      int moff = (cbeg >> 3) + tt * 8;
#pragma unroll
      for (int q = tid; q < 1024; q += 512) {
        int row = q >> 2, qq = q & 3;
        int4 mv = *reinterpret_cast<const int4*>(
            maskb + (size_t)(r0b + row) * 1024 + moff + qq * 16);
        mskl4[row * 5 + qq] = mv;
      }
      __syncthreads();
    }
    int bi = tt & 1;
    bool more = tt + 1 < ntile;
    // ---- early: next-tile staging loads ----
    int4 sg[NP];
    if (more) {
#pragma unroll
      for (int p = 0; p < NP; ++p) sg[p] = gw[(tt + 1) * (F * 8) + tid + p * 512];
    }
    int tmod = (tt & 7) * 8;
    unsigned long long mv0 =
        *reinterpret_cast<const unsigned long long*>(mskb + mrow0 + tmod);
    unsigned long long mv1 =
        *reinterpret_cast<const unsigned long long*>(mskb + mrow1 + tmod);
    int cl = tt * 64 + kg * 8;
    __builtin_amdgcn_sched_barrier(0);
    // ---- compute on buf bi ----
    {  // ks = 0
      const unsigned short* lbk = &lds[bi][0];
      bf16x8 bfrag[F / 16];
#pragma unroll
      for (int t = 0; t < F / 16; ++t)
        bfrag[t] = *reinterpret_cast<const bf16x8*>(lbk + t * (16 * RS) + rowoff);
      float4 bA0 = *reinterpret_cast<const float4*>(&Bl[cl]);
      float4 bA1 = *reinterpret_cast<const float4*>(&Bl[cl + 4]);
      float4 dA0 = *reinterpret_cast<const float4*>(&Dl[cl]);
      float4 dA1 = *reinterpret_cast<const float4*>(&Dl[cl + 4]);
      unsigned sh = kg * 8;
      bf16x8 af0 = buildp(ac0.x, ac0.y, bA0, bA1, dA0, dA1, (unsigned)(mv0 >> sh) & 0xffu);
      accl0 = __builtin_amdgcn_mfma_f32_16x16x32_bf16(af0, ones, accl0, 0, 0, 0);
#pragma unroll
      for (int t = 0; t < F / 16; ++t)
        acc0[t] = __builtin_amdgcn_mfma_f32_16x16x32_bf16(af0, bfrag[t], acc0[t], 0, 0, 0);
      bf16x8 af1 = buildp(ac1.x, ac1.y, bA0, bA1, dA0, dA1, (unsigned)(mv1 >> sh) & 0xffu);
      accl1 = __builtin_amdgcn_mfma_f32_16x16x32_bf16(af1, ones, accl1, 0, 0, 0);
#pragma unroll
      for (int t = 0; t < F / 16; ++t)
        acc1[t] = __builtin_amdgcn_mfma_f32_16x16x32_bf16(af1, bfrag[t], acc1[t], 0, 0, 0);
    }
    {  // ks = 1
      const unsigned short* lbk = &lds[bi][F * RS];
      bf16x8 bfrag[F / 16];
#pragma unroll
      for (int t = 0; t < F / 16; ++t)
        bfrag[t] = *reinterpret_cast<const bf16x8*>(lbk + t * (16 * RS) + rowoff);
      float4 bB0 = *reinterpret_cast<const float4*>(&Bl[cl + 32]);
      float4 bB1 = *reinterpret_cast<const float4*>(&Bl[cl + 36]);
      float4 dB0 = *reinterpret_cast<const float4*>(&Dl[cl + 32]);
      float4 dB1 = *reinterpret_cast<const float4*>(&Dl[cl + 36]);
      unsigned sh = 32 + kg * 8;
      bf16x8 af0 = buildp(ac0.x, ac0.y, bB0, bB1, dB0, dB1, (unsigned)(mv0 >> sh) & 0xffu);
      accl0 = __builtin_amdgcn_mfma_f32_16x16x32_bf16(af0, ones, accl0, 0, 0, 0);
#pragma unroll
      for (int t = 0; t < F / 16; ++t)
        acc0[t] = __builtin_amdgcn_mfma_f32_16x16x32_bf16(af0, bfrag[t], acc0[t], 0, 0, 0);
      bf16x8 af1 = buildp(ac1.x, ac1.y, bB0, bB1, dB0, dB1, (unsigned)(mv1 >> sh) & 0xffu);
      accl1 = __builtin_amdgcn_mfma_f32_16x16x32_bf16(af1, ones, accl1, 0, 0, 0);
#pragma unroll
      for (int t = 0; t < F / 16; ++t)
        acc1[t] = __builtin_amdgcn_mfma_f32_16x16x32_bf16(af1, bfrag[t], acc1[t], 0, 0, 0);
    }
    __builtin_amdgcn_sched_barrier(0);
    // ---- late: LDS write of staged tile ----
    if (more) {
#pragma unroll
      for (int p = 0; p < NP; ++p)
        *reinterpret_cast<int4*>(&lds[bi ^ 1][sdest[p]]) = sg[p];
    }
    __syncthreads();
  }

  if (rsub == 0) {
#pragma unroll
    for (int q = 0; q < 4; ++q) {
      pl[(size_t)(r0 + kg * 4 + q) * S + by] = accl0[q];
      pl[(size_t)(r0 + 16 + kg * 4 + q) * S + by] = accl1[q];
    }
  }
#pragma unroll
  for (int t = 0; t < F / 16; ++t) {
    int col = t * 16 + rsub;
#pragma unroll
    for (int q = 0; q < 4; ++q) {
      pacc[((size_t)(r0 + kg * 4 + q) * S + by) * F + col] = f2bf(acc0[t][q]);
      pacc[((size_t)(r0 + 16 + kg * 4 + q) * S + by) * F + col] = f2bf(acc1[t][q]);
    }
  }
}

// ====== whs2e: epi1 fused (pacc1/pl1 -> ELU h1 tile in LDS) + whs (F=64) + pmax2 ======
__global__ __launch_bounds__(128) void whs2e_kernel(
    const unsigned short* __restrict__ pacc1, const float* __restrict__ pl1,
    const float* __restrict__ W2, const float* __restrict__ a2,
    unsigned short* __restrict__ WhT2, float* __restrict__ s_src2,
    float* __restrict__ s_dst2, float* __restrict__ pmax2, int S) {
  __shared__ float hsh[16][128];
  __shared__ float sdv[16];
  int tid = threadIdx.x;
  int r0 = blockIdx.x * 16;
  int c2 = tid & 63, half = tid >> 6;
  for (int i = 0; i < 8; ++i) {
    int rr = r0 + half * 8 + i;
    float l = 0.f;
    for (int s = 0; s < S; ++s) l += pl1[(size_t)rr * S + s];
    float a0 = 0.f, a1v = 0.f;
    for (int s = 0; s < S; ++s) {
      unsigned u = *reinterpret_cast<const unsigned*>(
          pacc1 + ((size_t)rr * S + s) * 128 + c2 * 2);
      a0 += bf2f((unsigned short)(u & 0xffffu));
      a1v += bf2f((unsigned short)(u >> 16));
    }
    float v0 = a0 / l, v1 = a1v / l;
    v0 = v0 > 0.f ? v0 : expm1f(v0);
    v1 = v1 > 0.f ? v1 : expm1f(v1);
    hsh[half * 8 + i][c2 * 2] = v0;
    hsh[half * 8 + i][c2 * 2 + 1] = v1;
  }
  __syncthreads();
  float acc2[8];
#pragma unroll
  for (int r = 0; r < 8; ++r) acc2[r] = 0.f;
  const float4* w24 = reinterpret_cast<const float4*>(W2 + (size_t)c2 * 128);
#pragma unroll 4
  for (int k4 = 0; k4 < 32; ++k4) {
    float4 w = w24[k4];
#pragma unroll
    for (int r = 0; r < 8; ++r) {
      float4 xv = *reinterpret_cast<const float4*>(&hsh[half * 8 + r][k4 * 4]);
      acc2[r] = fmaf(xv.x, w.x, acc2[r]);
      acc2[r] = fmaf(xv.y, w.y, acc2[r]);
      acc2[r] = fmaf(xv.z, w.z, acc2[r]);
      acc2[r] = fmaf(xv.w, w.w, acc2[r]);
    }
  }
  float asrc = a2[c2], adst = a2[64 + c2];
  int lane = tid & 63;
#pragma unroll
  for (int r = 0; r < 8; ++r) {
    int rr = r0 + half * 8 + r;
    WhT2[(size_t)(rr >> 5) * (64 * 32) + (size_t)c2 * 32 + (rr & 31)] = f2bf(acc2[r]);
    float vs = acc2[r] * asrc, vd = acc2[r] * adst;
#pragma unroll
    for (int off = 32; off; off >>= 1) {
      vs += __shfl_xor(vs, off);
      vd += __shfl_xor(vd, off);
    }
    if (lane == 0) { s_src2[rr] = vs; s_dst2[rr] = vd; sdv[half * 8 + r] = vd; }
  }
  __syncthreads();
  if (tid == 0) {
    float m = sdv[0];
#pragma unroll
    for (int i = 1; i < 16; ++i) m = fmaxf(m, sdv[i]);
    pmax2[blockIdx.x] = m;
  }
}

// -------- epi2: out = (sum_s pacc2) / (sum_s l), no ELU --------
__global__ void epi_kernel(const unsigned short* __restrict__ pacc,
                           const float* __restrict__ pl, float* __restrict__ out, int S) {
  int idx = blockIdx.x * 256 + threadIdx.x;
  int row = idx >> 6, c = idx & 63;
  float l = 0.f, a = 0.f;
  for (int s = 0; s < S; ++s) {
    l += pl[(size_t)row * S + s];
    a += bf2f(pacc[((size_t)row * S + s) * 64 + c]);
  }
  out[idx] = a / l;
}

extern "C" void kernel_launch(void* const* d_in, const int* in_sizes, int n_in,
                              void* d_out, int out_size, void* d_ws, size_t ws_size,
                              hipStream_t stream) {
  const float* x  = (const float*)d_in[0];
  const int* adj  = (const int*)d_in[1];
  const float* Wp = (const float*)d_in[2];
  const float* bp = (const float*)d_in[3];
  const float* W1 = (const float*)d_in[4];
  const float* a1 = (const float*)d_in[5];
  const float* W2 = (const float*)d_in[6];
  const float* a2 = (const float*)d_in[7];
  float* out = (float*)d_out;

  // workspace: 18 MiB fixed + S*3 MiB (bf16 partials)
  int S = 4;
  if (ws_size >= (18ull + 48) * 1024 * 1024) S = 16;
  else if (ws_size >= (18ull + 24) * 1024 * 1024) S = 8;
  int cps = 8192 / S;

  char* ws = (char*)d_ws;
  unsigned short* WhT1 = (unsigned short*)(ws + 0);             // 0-2 MiB
  unsigned short* WhT2 = (unsigned short*)(ws + (2ull << 20));  // 2-3
  char* sm = ws + (3ull << 20);
  float* s_src1 = (float*)(sm + 0 * 32768);
  float* s_dst1 = (float*)(sm + 1 * 32768);
  float* s_src2 = (float*)(sm + 2 * 32768);
  float* s_dst2 = (float*)(sm + 3 * 32768);
  float* pmax1  = (float*)(sm + 4 * 32768);
  float* pmax2  = (float*)(sm + 4 * 32768 + 4096);
  unsigned char* maskb = (unsigned char*)(ws + (8ull << 20));   // 8-16 MiB
  float* pl1    = (float*)(ws + (16ull << 20));                 // 16-17
  float* pl2    = (float*)(ws + (17ull << 20));                 // 17-18
  unsigned short* pacc1 = (unsigned short*)(ws + (18ull << 20));        // S*2 MiB
  unsigned short* pacc2 = pacc1 + (size_t)S * 8192 * 128;               // S*1 MiB

  fused0_kernel<<<2560, 256, 0, stream>>>(adj, maskb, x, Wp, bp, W1, a1, WhT1,
                                          s_src1, s_dst1, pmax1);
  attn_kernel<128><<<dim3(32, S), 512, 0, stream>>>(
      maskb, s_src1, s_dst1, pmax1, WhT1, pacc1, pl1, cps, S);
  whs2e_kernel<<<512, 128, 0, stream>>>(pacc1, pl1, W2, a2, WhT2, s_src2, s_dst2,
                                        pmax2, S);
  attn_kernel<64><<<dim3(32, S), 512, 0, stream>>>(
      maskb, s_src2, s_dst2, pmax2, WhT2, pacc2, pl2, cps, S);
  epi_kernel<<<2048, 256, 0, stream>>>(pacc2, pl2, out, S);
}

// Round 11
// 199.516 us; speedup vs baseline: 1.1351x; 1.0056x over previous
//
#include <hip/hip_runtime.h>
#include <hip/hip_bf16.h>

typedef short bf16x8 __attribute__((ext_vector_type(8)));
typedef float f32x4 __attribute__((ext_vector_type(4)));
typedef unsigned int u32x4 __attribute__((ext_vector_type(4)));

static __device__ __forceinline__ unsigned short f2bf(float f) {
  unsigned int u = __builtin_bit_cast(unsigned int, f);
  u += 0x7fffu + ((u >> 16) & 1u);
  return (unsigned short)(u >> 16);
}
static __device__ __forceinline__ float bf2f(unsigned short b) {
  unsigned int u = ((unsigned int)b) << 16;
  return __builtin_bit_cast(float, u);
}

// ============ fused0: blocks 0-511 proj+whs1 (+pmax1); blocks 512-2559 adj->mask ============
__global__ __launch_bounds__(256) void fused0_kernel(
    const int* __restrict__ adj, unsigned char* __restrict__ maskb,
    const float* __restrict__ x, const float* __restrict__ Wp,
    const float* __restrict__ bp, const float* __restrict__ W1,
    const float* __restrict__ a1, unsigned short* __restrict__ WhT1,
    float* __restrict__ s_src1, float* __restrict__ s_dst1, float* __restrict__ pmax1) {
  __shared__ float xs[16][256];
  __shared__ float hsh[16][128];
  __shared__ float rsv[2][16][2];
  __shared__ float sdv[16];
  int tid = threadIdx.x;
  int b = blockIdx.x;
  if (b >= 512) {  // ---- mask part: 1 wave per row, perfectly sequential stream ----
    int wid = (b - 512) * 4 + (tid >> 6);
    int lane = tid & 63;
    const int4* ap = reinterpret_cast<const int4*>(adj + (size_t)wid * 8192);
    unsigned char* mrow = maskb + (size_t)wid * 1024;
#pragma unroll 4
    for (int it = 0; it < 16; ++it) {
      int cbase = it * 512;
      int4 a0 = ap[(cbase >> 2) + lane * 2];
      int4 a1v = ap[(cbase >> 2) + lane * 2 + 1];
      unsigned int mb = (unsigned)((a0.x > 0) | ((a0.y > 0) << 1) | ((a0.z > 0) << 2) |
                                   ((a0.w > 0) << 3) | ((a1v.x > 0) << 4) |
                                   ((a1v.y > 0) << 5) | ((a1v.z > 0) << 6) |
                                   ((a1v.w > 0) << 7));
      mrow[(cbase >> 3) + lane] = (unsigned char)mb;
    }
    return;
  }
  // ---- proj + whs1 part: 16 rows, 256 threads (j = tid&127, half = tid>>7) ----
  int r0 = b * 16;
  int j = tid & 127, half = tid >> 7;
  for (int t = tid; t < 16 * 256; t += 256)
    xs[t >> 8][t & 255] = x[(size_t)(r0 + (t >> 8)) * 256 + (t & 255)];
  __syncthreads();
  {
    float acc[8];
#pragma unroll
    for (int r = 0; r < 8; ++r) acc[r] = 0.f;
    const float4* wp4 = reinterpret_cast<const float4*>(Wp + (size_t)j * 256);
#pragma unroll 4
    for (int k4 = 0; k4 < 64; ++k4) {
      float4 w = wp4[k4];
#pragma unroll
      for (int r = 0; r < 8; ++r) {
        float4 xv = *reinterpret_cast<const float4*>(&xs[half * 8 + r][k4 * 4]);
        acc[r] = fmaf(xv.x, w.x, acc[r]);
        acc[r] = fmaf(xv.y, w.y, acc[r]);
        acc[r] = fmaf(xv.z, w.z, acc[r]);
        acc[r] = fmaf(xv.w, w.w, acc[r]);
      }
    }
    float bb = bp[j];
#pragma unroll
    for (int r = 0; r < 8; ++r) {
      float v = acc[r] + bb;
      hsh[half * 8 + r][j] = v > 0.f ? v : 0.f;
    }
  }
  __syncthreads();
  {
    float acc2[8];
#pragma unroll
    for (int r = 0; r < 8; ++r) acc2[r] = 0.f;
    const float4* w14 = reinterpret_cast<const float4*>(W1 + (size_t)j * 128);
#pragma unroll 4
    for (int k4 = 0; k4 < 32; ++k4) {
      float4 w = w14[k4];
#pragma unroll
      for (int r = 0; r < 8; ++r) {
        float4 xv = *reinterpret_cast<const float4*>(&hsh[half * 8 + r][k4 * 4]);
        acc2[r] = fmaf(xv.x, w.x, acc2[r]);
        acc2[r] = fmaf(xv.y, w.y, acc2[r]);
        acc2[r] = fmaf(xv.z, w.z, acc2[r]);
        acc2[r] = fmaf(xv.w, w.w, acc2[r]);
      }
    }
    float asrc = a1[j], adst = a1[128 + j];
    int lane = tid & 63, wv = tid >> 6;
#pragma unroll
    for (int r = 0; r < 8; ++r) {
      int rr = r0 + half * 8 + r;
      WhT1[(size_t)(rr >> 5) * (128 * 32) + (size_t)j * 32 + (rr & 31)] = f2bf(acc2[r]);
      float vs = acc2[r] * asrc, vd = acc2[r] * adst;
#pragma unroll
      for (int off = 32; off; off >>= 1) {
        vs += __shfl_xor(vs, off);
        vd += __shfl_xor(vd, off);
      }
      if (lane == 0) { rsv[0][half * 8 + r][wv & 1] = vs; rsv[1][half * 8 + r][wv & 1] = vd; }
    }
    __syncthreads();
    if (tid < 16) {
      float vs = rsv[0][tid][0] + rsv[0][tid][1];
      float vd = rsv[1][tid][0] + rsv[1][tid][1];
      s_src1[r0 + tid] = vs;
      s_dst1[r0 + tid] = vd;
      sdv[tid] = vd;
    }
    __syncthreads();
    if (tid == 0) {
      float m = sdv[0];
#pragma unroll
      for (int i = 1; i < 16; ++i) m = fmaxf(m, sdv[i]);
      pmax1[b] = m;
    }
  }
}

// p = max(A*B, C*D) masked = exact softmax weight exp(lrelu(e)-m); pack pair->bf16 trunc
static __device__ __forceinline__ bf16x8 buildp(float Af, float Cf, float4 ba, float4 bb,
                                                float4 da, float4 db, unsigned int mb) {
  float bv[8] = {ba.x, ba.y, ba.z, ba.w, bb.x, bb.y, bb.z, bb.w};
  float dv[8] = {da.x, da.y, da.z, da.w, db.x, db.y, db.z, db.w};
  u32x4 pw;
#pragma unroll
  for (int q = 0; q < 4; ++q) {
    float plo = fmaxf(Af * bv[2 * q], Cf * dv[2 * q]);
    float phi = fmaxf(Af * bv[2 * q + 1], Cf * dv[2 * q + 1]);
    plo = ((mb >> (2 * q)) & 1u) ? plo : 0.f;
    phi = ((mb >> (2 * q + 1)) & 1u) ? phi : 0.f;
    pw[q] = __builtin_amdgcn_perm(__builtin_bit_cast(unsigned int, phi),
                                  __builtin_bit_cast(unsigned int, plo), 0x07060302u);
  }
  return __builtin_bit_cast(bf16x8, pw);
}

// ============ attn: 8-wave block, LDS WhT (padded) + LDS mask strip (chunked preload) ============
// __launch_bounds__(512,4): 4 waves/EU min => <=128 VGPR => 2 blocks/CU (16 waves/CU).
// (Previous (512,2) permitted 256 VGPR -> 1 block/CU: the occupancy bug this round fixes.)
template <int F>
__global__ __launch_bounds__(512, 4) void attn_kernel(
    const unsigned char* __restrict__ maskb, const float* __restrict__ s_src,
    const float* __restrict__ s_dst, const float* __restrict__ pmax,
    const unsigned short* __restrict__ WhT, unsigned short* __restrict__ pacc,
    float* __restrict__ pl, int cps, int S) {
  constexpr int NP = F / 64;        // int4 staging chunks per thread
  constexpr int RS = 40;            // padded WhT row stride in shorts
  __shared__ unsigned short lds[2][2 * F * RS];  // [buf][ks*F*RS + j*RS + col]
  __shared__ int4 mskl4[256 * 5];   // mask strip: 256 rows x 80B (64B data + 16B pad)
  __shared__ float Bl[2048], Dl[2048];
  __shared__ float2 ACl[256];
  __shared__ float red[8];
  int tid = threadIdx.x;
  int lane = tid & 63, wv = tid >> 6;
  int rsub = lane & 15, kg = lane >> 4;
  int r0b = blockIdx.x * 256;
  int r0 = r0b + wv * 32;
  int by = blockIdx.y;
  int cbeg = by * cps;
  int ntile = cps >> 6;
  const unsigned char* mskb = reinterpret_cast<const unsigned char*>(mskl4);

  // staging chunk -> padded LDS dest (shorts): ks*(F*RS) + j*RS + s8*8
  int sdest[NP];
#pragma unroll
  for (int p = 0; p < NP; ++p) {
    int c = tid + p * 512;
    int ks = c / (F * 4), rem = c % (F * 4);
    sdest[p] = ks * (F * RS) + (rem >> 2) * RS + (rem & 3) * 8;
  }

  // ---- prologue: fold g, fill B/D/AC, stage tile 0 ----
  float pv = pmax[tid & 511];
#pragma unroll
  for (int off = 32; off; off >>= 1) pv = fmaxf(pv, __shfl_xor(pv, off));
  if (lane == 0) red[wv] = pv;
  __syncthreads();
  float g = red[0];
#pragma unroll
  for (int i = 1; i < 8; ++i) g = fmaxf(g, red[i]);
  for (int t = tid; t < cps; t += 512) {
    float sd = s_dst[cbeg + t] - g;
    Bl[t] = __expf(sd);
    Dl[t] = __expf(0.2f * sd);
  }
  if (tid < 256) {
    float e0 = s_src[r0b + tid] + g;
    ACl[tid] = make_float2(__expf(fminf(0.8f * e0, 0.f)), __expf(fminf(-0.8f * e0, 0.f)));
  }
  const int4* gw = reinterpret_cast<const int4*>(WhT + (size_t)(cbeg >> 5) * (F * 32));
  {
    int4 s0[NP];
#pragma unroll
    for (int p = 0; p < NP; ++p) s0[p] = gw[tid + p * 512];
#pragma unroll
    for (int p = 0; p < NP; ++p)
      *reinterpret_cast<int4*>(&lds[0][sdest[p]]) = s0[p];
  }
  __syncthreads();

  float2 ac0 = ACl[wv * 32 + rsub], ac1 = ACl[wv * 32 + 16 + rsub];
  f32x4 acc0[F / 16], acc1[F / 16];
#pragma unroll
  for (int t = 0; t < F / 16; ++t) { acc0[t] = (f32x4)0.f; acc1[t] = (f32x4)0.f; }
  f32x4 accl0 = (f32x4)0.f, accl1 = (f32x4)0.f;
  bf16x8 ones;
#pragma unroll
  for (int jj = 0; jj < 8; ++jj) ones[jj] = (short)0x3F80;  // bf16 1.0
  const int rowoff = rsub * RS + kg * 8;
  const int mrow0 = (wv * 32 + rsub) * 80, mrow1 = (wv * 32 + 16 + rsub) * 80;

  for (int tt = 0; tt < ntile; ++tt) {
    // ---- chunk boundary: preload 8 tiles' mask strip (coalesced, full 64B lines) ----
    if ((tt & 7) == 0) {
      int moff = (cbeg >> 3) + tt * 8;
#pragma unroll
      for (int q = tid; q < 1024; q += 512) {
        int row = q >> 2, qq = q & 3;
        int4 mv = *reinterpret_cast<const int4*>(
            maskb + (size_t)(r0b + row) * 1024 + moff + qq * 16);
        mskl4[row * 5 + qq] = mv;
      }
      __syncthreads();
    }
    int bi = tt & 1;
    bool more = tt + 1 < ntile;
    // ---- early: next-tile staging loads ----
    int4 sg[NP];
    if (more) {
#pragma unroll
      for (int p = 0; p < NP; ++p) sg[p] = gw[(tt + 1) * (F * 8) + tid + p * 512];
    }
    int tmod = (tt & 7) * 8;
    unsigned long long mv0 =
        *reinterpret_cast<const unsigned long long*>(mskb + mrow0 + tmod);
    unsigned long long mv1 =
        *reinterpret_cast<const unsigned long long*>(mskb + mrow1 + tmod);
    int cl = tt * 64 + kg * 8;
    __builtin_amdgcn_sched_barrier(0);
    // ---- compute on buf bi ----
    {  // ks = 0
      const unsigned short* lbk = &lds[bi][0];
      bf16x8 bfrag[F / 16];
#pragma unroll
      for (int t = 0; t < F / 16; ++t)
        bfrag[t] = *reinterpret_cast<const bf16x8*>(lbk + t * (16 * RS) + rowoff);
      float4 bA0 = *reinterpret_cast<const float4*>(&Bl[cl]);
      float4 bA1 = *reinterpret_cast<const float4*>(&Bl[cl + 4]);
      float4 dA0 = *reinterpret_cast<const float4*>(&Dl[cl]);
      float4 dA1 = *reinterpret_cast<const float4*>(&Dl[cl + 4]);
      unsigned sh = kg * 8;
      bf16x8 af0 = buildp(ac0.x, ac0.y, bA0, bA1, dA0, dA1, (unsigned)(mv0 >> sh) & 0xffu);
      accl0 = __builtin_amdgcn_mfma_f32_16x16x32_bf16(af0, ones, accl0, 0, 0, 0);
#pragma unroll
      for (int t = 0; t < F / 16; ++t)
        acc0[t] = __builtin_amdgcn_mfma_f32_16x16x32_bf16(af0, bfrag[t], acc0[t], 0, 0, 0);
      bf16x8 af1 = buildp(ac1.x, ac1.y, bA0, bA1, dA0, dA1, (unsigned)(mv1 >> sh) & 0xffu);
      accl1 = __builtin_amdgcn_mfma_f32_16x16x32_bf16(af1, ones, accl1, 0, 0, 0);
#pragma unroll
      for (int t = 0; t < F / 16; ++t)
        acc1[t] = __builtin_amdgcn_mfma_f32_16x16x32_bf16(af1, bfrag[t], acc1[t], 0, 0, 0);
    }
    {  // ks = 1
      const unsigned short* lbk = &lds[bi][F * RS];
      bf16x8 bfrag[F / 16];
#pragma unroll
      for (int t = 0; t < F / 16; ++t)
        bfrag[t] = *reinterpret_cast<const bf16x8*>(lbk + t * (16 * RS) + rowoff);
      float4 bB0 = *reinterpret_cast<const float4*>(&Bl[cl + 32]);
      float4 bB1 = *reinterpret_cast<const float4*>(&Bl[cl + 36]);
      float4 dB0 = *reinterpret_cast<const float4*>(&Dl[cl + 32]);
      float4 dB1 = *reinterpret_cast<const float4*>(&Dl[cl + 36]);
      unsigned sh = 32 + kg * 8;
      bf16x8 af0 = buildp(ac0.x, ac0.y, bB0, bB1, dB0, dB1, (unsigned)(mv0 >> sh) & 0xffu);
      accl0 = __builtin_amdgcn_mfma_f32_16x16x32_bf16(af0, ones, accl0, 0, 0, 0);
#pragma unroll
      for (int t = 0; t < F / 16; ++t)
        acc0[t] = __builtin_amdgcn_mfma_f32_16x16x32_bf16(af0, bfrag[t], acc0[t], 0, 0, 0);
      bf16x8 af1 = buildp(ac1.x, ac1.y, bB0, bB1, dB0, dB1, (unsigned)(mv1 >> sh) & 0xffu);
      accl1 = __builtin_amdgcn_mfma_f32_16x16x32_bf16(af1, ones, accl1, 0, 0, 0);
#pragma unroll
      for (int t = 0; t < F / 16; ++t)
        acc1[t] = __builtin_amdgcn_mfma_f32_16x16x32_bf16(af1, bfrag[t], acc1[t], 0, 0, 0);
    }
    __builtin_amdgcn_sched_barrier(0);
    // ---- late: LDS write of staged tile ----
    if (more) {
#pragma unroll
      for (int p = 0; p < NP; ++p)
        *reinterpret_cast<int4*>(&lds[bi ^ 1][sdest[p]]) = sg[p];
    }
    __syncthreads();
  }

  if (rsub == 0) {
#pragma unroll
    for (int q = 0; q < 4; ++q) {
      pl[(size_t)(r0 + kg * 4 + q) * S + by] = accl0[q];
      pl[(size_t)(r0 + 16 + kg * 4 + q) * S + by] = accl1[q];
    }
  }
#pragma unroll
  for (int t = 0; t < F / 16; ++t) {
    int col = t * 16 + rsub;
#pragma unroll
    for (int q = 0; q < 4; ++q) {
      pacc[((size_t)(r0 + kg * 4 + q) * S + by) * F + col] = f2bf(acc0[t][q]);
      pacc[((size_t)(r0 + 16 + kg * 4 + q) * S + by) * F + col] = f2bf(acc1[t][q]);
    }
  }
}

// ====== whs2e: epi1 fused (pacc1/pl1 -> ELU h1 tile in LDS) + whs (F=64) + pmax2 ======
__global__ __launch_bounds__(128) void whs2e_kernel(
    const unsigned short* __restrict__ pacc1, const float* __restrict__ pl1,
    const float* __restrict__ W2, const float* __restrict__ a2,
    unsigned short* __restrict__ WhT2, float* __restrict__ s_src2,
    float* __restrict__ s_dst2, float* __restrict__ pmax2, int S) {
  __shared__ float hsh[16][128];
  __shared__ float sdv[16];
  int tid = threadIdx.x;
  int r0 = blockIdx.x * 16;
  int c2 = tid & 63, half = tid >> 6;
  for (int i = 0; i < 8; ++i) {
    int rr = r0 + half * 8 + i;
    float l = 0.f;
    for (int s = 0; s < S; ++s) l += pl1[(size_t)rr * S + s];
    float a0 = 0.f, a1v = 0.f;
    for (int s = 0; s < S; ++s) {
      unsigned u = *reinterpret_cast<const unsigned*>(
          pacc1 + ((size_t)rr * S + s) * 128 + c2 * 2);
      a0 += bf2f((unsigned short)(u & 0xffffu));
      a1v += bf2f((unsigned short)(u >> 16));
    }
    float v0 = a0 / l, v1 = a1v / l;
    v0 = v0 > 0.f ? v0 : expm1f(v0);
    v1 = v1 > 0.f ? v1 : expm1f(v1);
    hsh[half * 8 + i][c2 * 2] = v0;
    hsh[half * 8 + i][c2 * 2 + 1] = v1;
  }
  __syncthreads();
  float acc2[8];
#pragma unroll
  for (int r = 0; r < 8; ++r) acc2[r] = 0.f;
  const float4* w24 = reinterpret_cast<const float4*>(W2 + (size_t)c2 * 128);
#pragma unroll 4
  for (int k4 = 0; k4 < 32; ++k4) {
    float4 w = w24[k4];
#pragma unroll
    for (int r = 0; r < 8; ++r) {
      float4 xv = *reinterpret_cast<const float4*>(&hsh[half * 8 + r][k4 * 4]);
      acc2[r] = fmaf(xv.x, w.x, acc2[r]);
      acc2[r] = fmaf(xv.y, w.y, acc2[r]);
      acc2[r] = fmaf(xv.z, w.z, acc2[r]);
      acc2[r] = fmaf(xv.w, w.w, acc2[r]);
    }
  }
  float asrc = a2[c2], adst = a2[64 + c2];
  int lane = tid & 63;
#pragma unroll
  for (int r = 0; r < 8; ++r) {
    int rr = r0 + half * 8 + r;
    WhT2[(size_t)(rr >> 5) * (64 * 32) + (size_t)c2 * 32 + (rr & 31)] = f2bf(acc2[r]);
    float vs = acc2[r] * asrc, vd = acc2[r] * adst;
#pragma unroll
    for (int off = 32; off; off >>= 1) {
      vs += __shfl_xor(vs, off);
      vd += __shfl_xor(vd, off);
    }
    if (lane == 0) { s_src2[rr] = vs; s_dst2[rr] = vd; sdv[half * 8 + r] = vd; }
  }
  __syncthreads();
  if (tid == 0) {
    float m = sdv[0];
#pragma unroll
    for (int i = 1; i < 16; ++i) m = fmaxf(m, sdv[i]);
    pmax2[blockIdx.x] = m;
  }
}

// -------- epi2: out = (sum_s pacc2) / (sum_s l), no ELU --------
__global__ void epi_kernel(const unsigned short* __restrict__ pacc,
                           const float* __restrict__ pl, float* __restrict__ out, int S) {
  int idx = blockIdx.x * 256 + threadIdx.x;
  int row = idx >> 6, c = idx & 63;
  float l = 0.f, a = 0.f;
  for (int s = 0; s < S; ++s) {
    l += pl[(size_t)row * S + s];
    a += bf2f(pacc[((size_t)row * S + s) * 64 + c]);
  }
  out[idx] = a / l;
}

extern "C" void kernel_launch(void* const* d_in, const int* in_sizes, int n_in,
                              void* d_out, int out_size, void* d_ws, size_t ws_size,
                              hipStream_t stream) {
  const float* x  = (const float*)d_in[0];
  const int* adj  = (const int*)d_in[1];
  const float* Wp = (const float*)d_in[2];
  const float* bp = (const float*)d_in[3];
  const float* W1 = (const float*)d_in[4];
  const float* a1 = (const float*)d_in[5];
  const float* W2 = (const float*)d_in[6];
  const float* a2 = (const float*)d_in[7];
  float* out = (float*)d_out;

  // workspace: 18 MiB fixed + S*3 MiB (bf16 partials)
  int S = 4;
  if (ws_size >= (18ull + 48) * 1024 * 1024) S = 16;
  else if (ws_size >= (18ull + 24) * 1024 * 1024) S = 8;
  int cps = 8192 / S;

  char* ws = (char*)d_ws;
  unsigned short* WhT1 = (unsigned short*)(ws + 0);             // 0-2 MiB
  unsigned short* WhT2 = (unsigned short*)(ws + (2ull << 20));  // 2-3
  char* sm = ws + (3ull << 20);
  float* s_src1 = (float*)(sm + 0 * 32768);
  float* s_dst1 = (float*)(sm + 1 * 32768);
  float* s_src2 = (float*)(sm + 2 * 32768);
  float* s_dst2 = (float*)(sm + 3 * 32768);
  float* pmax1  = (float*)(sm + 4 * 32768);
  float* pmax2  = (float*)(sm + 4 * 32768 + 4096);
  unsigned char* maskb = (unsigned char*)(ws + (8ull << 20));   // 8-16 MiB
  float* pl1    = (float*)(ws + (16ull << 20));                 // 16-17
  float* pl2    = (float*)(ws + (17ull << 20));                 // 17-18
  unsigned short* pacc1 = (unsigned short*)(ws + (18ull << 20));        // S*2 MiB
  unsigned short* pacc2 = pacc1 + (size_t)S * 8192 * 128;               // S*1 MiB

  fused0_kernel<<<2560, 256, 0, stream>>>(adj, maskb, x, Wp, bp, W1, a1, WhT1,
                                          s_src1, s_dst1, pmax1);
  attn_kernel<128><<<dim3(32, S), 512, 0, stream>>>(
      maskb, s_src1, s_dst1, pmax1, WhT1, pacc1, pl1, cps, S);
  whs2e_kernel<<<512, 128, 0, stream>>>(pacc1, pl1, W2, a2, WhT2, s_src2, s_dst2,
                                        pmax2, S);
  attn_kernel<64><<<dim3(32, S), 512, 0, stream>>>(
      maskb, s_src2, s_dst2, pmax2, WhT2, pacc2, pl2, cps, S);
  epi_kernel<<<2048, 256, 0, stream>>>(pacc2, pl2, out, S);
}